// Round 3
// baseline (236.606 us; speedup 1.0000x reference)
//
#include <hip/hip_runtime.h>

// Problem geometry (fixed by the reference):
//   probs: (B=2, C=2, D=32, H=512, W=512) fp32
//   mask : (B=2, D=32, H=512, W=512)      int32, values {0,1,2}; 2 = ignore -> class 0
// Output: scalar fp32 = mean over all B*C*D*H*W of (probs - onehot)^2
static constexpr long long DHW       = 32LL * 512 * 512;   // 8388608 = 1<<23
static constexpr long long N_SPATIAL = 2LL * DHW;          // 16777216
static constexpr long long N_TOTAL   = 2LL * N_SPATIAL;    // 33554432

static constexpr int GRID  = 2048;
static constexpr int BLOCK = 256;
static constexpr int ITERS = 8;
static constexpr long long NVEC   = N_SPATIAL / 4;             // 4194304 float4 chunks
static constexpr long long STRIDE = (long long)GRID * BLOCK;   // 524288
static_assert(NVEC == ITERS * STRIDE, "exact trip count");

__global__ __launch_bounds__(BLOCK) void betti_mse_partial(const float* __restrict__ probs,
                                                           const int*   __restrict__ mask,
                                                           double*      __restrict__ partial) {
    const long long v0 = (long long)blockIdx.x * BLOCK + threadIdx.x;

    // Phase 1: issue ALL loads up front (24 vector loads, ~24 KB in flight per wave).
    float4 P0[ITERS], P1[ITERS];
    int4   M[ITERS];
    #pragma unroll
    for (int i = 0; i < ITERS; ++i) {
        const long long s    = (v0 + (long long)i * STRIDE) << 2;  // spatial flat idx
        const long long b    = s >> 23;                            // s / DHW
        const long long rest = s & (DHW - 1);                      // s % DHW
        const long long base = (b << 24) + rest;                   // b*C*DHW + rest
        P0[i] = *reinterpret_cast<const float4*>(probs + base);         // c=0
        P1[i] = *reinterpret_cast<const float4*>(probs + base + DHW);   // c=1
        M[i]  = *reinterpret_cast<const int4*>(mask + s);
    }

    // Phase 2: consume.
    float local = 0.0f;
    #pragma unroll
    for (int i = 0; i < ITERS; ++i) {
        const float t0 = (M[i].x == 1) ? 1.0f : 0.0f;
        const float t1 = (M[i].y == 1) ? 1.0f : 0.0f;
        const float t2 = (M[i].z == 1) ? 1.0f : 0.0f;
        const float t3 = (M[i].w == 1) ? 1.0f : 0.0f;
        float d;
        d = P0[i].x - (1.0f - t0); local += d * d;
        d = P0[i].y - (1.0f - t1); local += d * d;
        d = P0[i].z - (1.0f - t2); local += d * d;
        d = P0[i].w - (1.0f - t3); local += d * d;
        d = P1[i].x - t0;          local += d * d;
        d = P1[i].y - t1;          local += d * d;
        d = P1[i].z - t2;          local += d * d;
        d = P1[i].w - t3;          local += d * d;
    }

    #pragma unroll
    for (int off = 32; off > 0; off >>= 1)
        local += __shfl_down(local, off, 64);

    __shared__ float wsum[4];
    const int lane = threadIdx.x & 63;
    const int wid  = threadIdx.x >> 6;
    if (lane == 0) wsum[wid] = local;
    __syncthreads();
    if (threadIdx.x == 0)
        partial[blockIdx.x] = (double)(wsum[0] + wsum[1] + wsum[2] + wsum[3]);
}

__global__ __launch_bounds__(BLOCK) void betti_mse_final(const double* __restrict__ partial,
                                                         float* __restrict__ out) {
    double local = 0.0;
    #pragma unroll
    for (int k = 0; k < GRID / BLOCK; ++k)   // 8 partials per thread
        local += partial[threadIdx.x + k * BLOCK];

    #pragma unroll
    for (int off = 32; off > 0; off >>= 1)
        local += __shfl_down(local, off, 64);

    __shared__ double wsum[4];
    const int lane = threadIdx.x & 63;
    const int wid  = threadIdx.x >> 6;
    if (lane == 0) wsum[wid] = local;
    __syncthreads();
    if (threadIdx.x == 0)
        out[0] = (float)((wsum[0] + wsum[1] + wsum[2] + wsum[3]) / (double)N_TOTAL);
}

extern "C" void kernel_launch(void* const* d_in, const int* in_sizes, int n_in,
                              void* d_out, int out_size, void* d_ws, size_t ws_size,
                              hipStream_t stream) {
    const float* probs   = (const float*)d_in[0];
    const int*   mask    = (const int*)d_in[1];
    float*       out     = (float*)d_out;
    double*      partial = (double*)d_ws;   // GRID doubles = 16 KB scratch

    betti_mse_partial<<<GRID, BLOCK, 0, stream>>>(probs, mask, partial);
    betti_mse_final<<<1, BLOCK, 0, stream>>>(partial, out);
}

// Round 5
// 216.550 us; speedup vs baseline: 1.0926x; 1.0926x over previous
//
#include <hip/hip_runtime.h>

// Problem geometry (fixed by the reference):
//   probs: (B=2, C=2, D=32, H=512, W=512) fp32
//   mask : (B=2, D=32, H=512, W=512)      int32, values {0,1,2}; 2 = ignore -> class 0
// Output: scalar fp32 = mean over all B*C*D*H*W of (probs - onehot)^2
static constexpr long long DHW       = 32LL * 512 * 512;   // 8388608 = 1<<23
static constexpr long long N_SPATIAL = 2LL * DHW;          // 16777216
static constexpr long long N_TOTAL   = 2LL * N_SPATIAL;    // 33554432

static constexpr int GRID  = 2048;
static constexpr int BLOCK = 256;
static constexpr int ITERS = 8;
static constexpr long long NVEC   = N_SPATIAL / 4;             // 4194304 float4 chunks
static constexpr long long STRIDE = (long long)GRID * BLOCK;   // 524288
static_assert(NVEC == ITERS * STRIDE, "exact trip count");

// Native clang vector types — required by __builtin_nontemporal_load
// (HIP_vector_type float4/int4 are structs and are rejected).
typedef float fx4 __attribute__((ext_vector_type(4)));
typedef int   ix4 __attribute__((ext_vector_type(4)));

__global__ __launch_bounds__(BLOCK) void betti_mse_partial(const float* __restrict__ probs,
                                                           const int*   __restrict__ mask,
                                                           double*      __restrict__ partial) {
    const long long v0 = (long long)blockIdx.x * BLOCK + threadIdx.x;

    // Batch all loads up front, NONTEMPORAL: bypass cache allocation on the
    // read path (global_load_dwordx4 ... nt). Theory: read-return path is
    // throttled by cache line-allocation, not by issue rate or HBM.
    fx4 P0[ITERS], P1[ITERS];
    ix4 M[ITERS];
    #pragma unroll
    for (int i = 0; i < ITERS; ++i) {
        const long long s    = (v0 + (long long)i * STRIDE) << 2;  // spatial flat idx
        const long long b    = s >> 23;                            // s / DHW
        const long long rest = s & (DHW - 1);                      // s % DHW
        const long long base = (b << 24) + rest;                   // b*C*DHW + rest
        P0[i] = __builtin_nontemporal_load(reinterpret_cast<const fx4*>(probs + base));
        P1[i] = __builtin_nontemporal_load(reinterpret_cast<const fx4*>(probs + base + DHW));
        M[i]  = __builtin_nontemporal_load(reinterpret_cast<const ix4*>(mask + s));
    }

    float local = 0.0f;
    #pragma unroll
    for (int i = 0; i < ITERS; ++i) {
        const float t0 = (M[i].x == 1) ? 1.0f : 0.0f;
        const float t1 = (M[i].y == 1) ? 1.0f : 0.0f;
        const float t2 = (M[i].z == 1) ? 1.0f : 0.0f;
        const float t3 = (M[i].w == 1) ? 1.0f : 0.0f;
        float d;
        d = P0[i].x - (1.0f - t0); local += d * d;
        d = P0[i].y - (1.0f - t1); local += d * d;
        d = P0[i].z - (1.0f - t2); local += d * d;
        d = P0[i].w - (1.0f - t3); local += d * d;
        d = P1[i].x - t0;          local += d * d;
        d = P1[i].y - t1;          local += d * d;
        d = P1[i].z - t2;          local += d * d;
        d = P1[i].w - t3;          local += d * d;
    }

    #pragma unroll
    for (int off = 32; off > 0; off >>= 1)
        local += __shfl_down(local, off, 64);

    __shared__ float wsum[4];
    const int lane = threadIdx.x & 63;
    const int wid  = threadIdx.x >> 6;
    if (lane == 0) wsum[wid] = local;
    __syncthreads();
    if (threadIdx.x == 0)
        partial[blockIdx.x] = (double)(wsum[0] + wsum[1] + wsum[2] + wsum[3]);
}

__global__ __launch_bounds__(BLOCK) void betti_mse_final(const double* __restrict__ partial,
                                                         float* __restrict__ out) {
    double local = 0.0;
    #pragma unroll
    for (int k = 0; k < GRID / BLOCK; ++k)   // 8 partials per thread
        local += partial[threadIdx.x + k * BLOCK];

    #pragma unroll
    for (int off = 32; off > 0; off >>= 1)
        local += __shfl_down(local, off, 64);

    __shared__ double wsum[4];
    const int lane = threadIdx.x & 63;
    const int wid  = threadIdx.x >> 6;
    if (lane == 0) wsum[wid] = local;
    __syncthreads();
    if (threadIdx.x == 0)
        out[0] = (float)((wsum[0] + wsum[1] + wsum[2] + wsum[3]) / (double)N_TOTAL);
}

extern "C" void kernel_launch(void* const* d_in, const int* in_sizes, int n_in,
                              void* d_out, int out_size, void* d_ws, size_t ws_size,
                              hipStream_t stream) {
    const float* probs   = (const float*)d_in[0];
    const int*   mask    = (const int*)d_in[1];
    float*       out     = (float*)d_out;
    double*      partial = (double*)d_ws;   // GRID doubles = 16 KB scratch

    betti_mse_partial<<<GRID, BLOCK, 0, stream>>>(probs, mask, partial);
    betti_mse_final<<<1, BLOCK, 0, stream>>>(partial, out);
}

// Round 6
// 215.769 us; speedup vs baseline: 1.0966x; 1.0036x over previous
//
#include <hip/hip_runtime.h>

// Problem geometry (fixed by the reference):
//   probs: (B=2, C=2, D=32, H=512, W=512) fp32
//   mask : (B=2, D=32, H=512, W=512)      int32, values {0,1,2}; 2 = ignore -> class 0
// Output: scalar fp32 = mean over all B*C*D*H*W of (probs - onehot)^2
static constexpr long long DHW       = 32LL * 512 * 512;   // 8388608 = 1<<23
static constexpr long long N_SPATIAL = 2LL * DHW;          // 16777216
static constexpr long long N_TOTAL   = 2LL * N_SPATIAL;    // 33554432

static constexpr int GRID  = 1024;   // 4 blocks/CU x 4 waves = 16 waves/CU
static constexpr int BLOCK = 256;
static constexpr int ITERS = 16;     // 48 NT loads (48 KB) in flight per wave
static constexpr long long NVEC   = N_SPATIAL / 4;             // 4194304 float4 chunks
static constexpr long long STRIDE = (long long)GRID * BLOCK;   // 262144
static_assert(NVEC == (long long)ITERS * STRIDE, "exact trip count");

// Native clang vector types — required by __builtin_nontemporal_load
// (HIP_vector_type float4/int4 are structs and are rejected).
typedef float fx4 __attribute__((ext_vector_type(4)));
typedef int   ix4 __attribute__((ext_vector_type(4)));

__global__ __launch_bounds__(BLOCK) void betti_mse_partial(const float* __restrict__ probs,
                                                           const int*   __restrict__ mask,
                                                           double*      __restrict__ partial) {
    const long long v0 = (long long)blockIdx.x * BLOCK + threadIdx.x;

    // Batch ALL loads up front, NONTEMPORAL (global_load_dwordx4 ... nt):
    // R5 established nt lifts the cache-allocation throttle on the read path.
    fx4 P0[ITERS], P1[ITERS];
    ix4 M[ITERS];
    #pragma unroll
    for (int i = 0; i < ITERS; ++i) {
        const long long s    = (v0 + (long long)i * STRIDE) << 2;  // spatial flat idx
        const long long b    = s >> 23;                            // s / DHW
        const long long rest = s & (DHW - 1);                      // s % DHW
        const long long base = (b << 24) + rest;                   // b*C*DHW + rest
        P0[i] = __builtin_nontemporal_load(reinterpret_cast<const fx4*>(probs + base));
        P1[i] = __builtin_nontemporal_load(reinterpret_cast<const fx4*>(probs + base + DHW));
        M[i]  = __builtin_nontemporal_load(reinterpret_cast<const ix4*>(mask + s));
    }

    float acc0 = 0.0f, acc1 = 0.0f;
    #pragma unroll
    for (int i = 0; i < ITERS; ++i) {
        const float t0 = (M[i].x == 1) ? 1.0f : 0.0f;
        const float t1 = (M[i].y == 1) ? 1.0f : 0.0f;
        const float t2 = (M[i].z == 1) ? 1.0f : 0.0f;
        const float t3 = (M[i].w == 1) ? 1.0f : 0.0f;
        float d;
        d = P0[i].x - (1.0f - t0); acc0 += d * d;
        d = P0[i].y - (1.0f - t1); acc1 += d * d;
        d = P0[i].z - (1.0f - t2); acc0 += d * d;
        d = P0[i].w - (1.0f - t3); acc1 += d * d;
        d = P1[i].x - t0;          acc0 += d * d;
        d = P1[i].y - t1;          acc1 += d * d;
        d = P1[i].z - t2;          acc0 += d * d;
        d = P1[i].w - t3;          acc1 += d * d;
    }
    float local = acc0 + acc1;

    #pragma unroll
    for (int off = 32; off > 0; off >>= 1)
        local += __shfl_down(local, off, 64);

    __shared__ float wsum[4];
    const int lane = threadIdx.x & 63;
    const int wid  = threadIdx.x >> 6;
    if (lane == 0) wsum[wid] = local;
    __syncthreads();
    if (threadIdx.x == 0)
        partial[blockIdx.x] = (double)(wsum[0] + wsum[1] + wsum[2] + wsum[3]);
}

__global__ __launch_bounds__(BLOCK) void betti_mse_final(const double* __restrict__ partial,
                                                         float* __restrict__ out) {
    double local = 0.0;
    #pragma unroll
    for (int k = 0; k < GRID / BLOCK; ++k)   // 4 partials per thread
        local += partial[threadIdx.x + k * BLOCK];

    #pragma unroll
    for (int off = 32; off > 0; off >>= 1)
        local += __shfl_down(local, off, 64);

    __shared__ double wsum[4];
    const int lane = threadIdx.x & 63;
    const int wid  = threadIdx.x >> 6;
    if (lane == 0) wsum[wid] = local;
    __syncthreads();
    if (threadIdx.x == 0)
        out[0] = (float)((wsum[0] + wsum[1] + wsum[2] + wsum[3]) / (double)N_TOTAL);
}

extern "C" void kernel_launch(void* const* d_in, const int* in_sizes, int n_in,
                              void* d_out, int out_size, void* d_ws, size_t ws_size,
                              hipStream_t stream) {
    const float* probs   = (const float*)d_in[0];
    const int*   mask    = (const int*)d_in[1];
    float*       out     = (float*)d_out;
    double*      partial = (double*)d_ws;   // GRID doubles = 8 KB scratch

    betti_mse_partial<<<GRID, BLOCK, 0, stream>>>(probs, mask, partial);
    betti_mse_final<<<1, BLOCK, 0, stream>>>(partial, out);
}